// Round 2
// 2195.363 us; speedup vs baseline: 3.6842x; 3.6842x over previous
//
#include <hip/hip_runtime.h>
#include <hip/hip_bf16.h>

// GIN + virtual node, 5 layers, N=100000, E=300000, G=4096, D=256.
// Atomic-free: CSR-by-dst gather for edge aggregation, sorted-batch segmented
// reduction for graph pooling. f32 everywhere except GEMM inner (bf16 MFMA).

typedef __attribute__((ext_vector_type(8))) short short8;
typedef __attribute__((ext_vector_type(4))) short short4v;
typedef __attribute__((ext_vector_type(4))) float float4v;

__device__ __forceinline__ short f2bf(float f) {
  unsigned u = __builtin_bit_cast(unsigned, f);
  unsigned r = (u + 0x7FFFu + ((u >> 16) & 1u)) >> 16;
  return (short)r;
}

// ---------------- weight transpose + bf16 convert: Wt[n][k] = W[k][n] -------
__global__ __launch_bounds__(256) void k_transpose_weights(
    const float* __restrict__ cW1, const float* __restrict__ cW2,
    const float* __restrict__ vW1, const float* __restrict__ vW2,
    short* __restrict__ Wt)
{
  __shared__ float tile[32][33];
  int id = blockIdx.y;
  const float* W;
  if (id < 5)       W = cW1 + (size_t)id * 65536;
  else if (id < 10) W = cW2 + (size_t)(id - 5) * 65536;
  else if (id < 14) W = vW1 + (size_t)(id - 10) * 65536;
  else              W = vW2 + (size_t)(id - 14) * 65536;
  short* O = Wt + (size_t)id * 65536;
  int k0 = (blockIdx.x >> 3) * 32;
  int n0 = (blockIdx.x & 7) * 32;
  int tid = threadIdx.x;
  int rr = tid >> 5, cc = tid & 31;
#pragma unroll
  for (int i = 0; i < 4; i++)
    tile[rr + i * 8][cc] = W[(size_t)(k0 + rr + i * 8) * 256 + n0 + cc];
  __syncthreads();
#pragma unroll
  for (int i = 0; i < 4; i++)
    O[(size_t)(n0 + rr + i * 8) * 256 + k0 + cc] = f2bf(tile[cc][rr + i * 8]);
}

// ---------------- small utility kernels ------------------------------------
__global__ __launch_bounds__(256) void k_vninit(float* vn, const float* vn_emb) {
  vn[(size_t)blockIdx.x * 256 + threadIdx.x] = vn_emb[threadIdx.x];
}

__global__ __launch_bounds__(256) void k_vnapply(float* vn, const float* scale,
                                                 const float* shift) {
  int t = blockIdx.x * 256 + threadIdx.x;
  int d = t & 255;
  float v = vn[t];
  vn[t] = fmaxf(fmaf(v, scale[d], shift[d]), 0.f);
}

// finalize BN stats -> scale/shift  (scale = g*rsqrt(var+eps), shift = b-mean*scale)
__global__ void k_finalize(const float* __restrict__ stats, const float* __restrict__ g,
                           const float* __restrict__ b, float* scale, float* shift,
                           float invCnt) {
  int d = threadIdx.x;
  float mean = stats[d] * invCnt;
  float var = stats[256 + d] * invCnt - mean * mean;
  float r = rsqrtf(fmaxf(var, 0.f) + 1e-5f);
  float sc = r * g[d];
  scale[d] = sc;
  shift[d] = b[d] - mean * sc;
}

// ---------------- CSR build ------------------------------------------------
__global__ __launch_bounds__(256) void k_count(const int* __restrict__ ei,
                                               int* cnt, int E) {
  int e = blockIdx.x * 256 + threadIdx.x;
  if (e < E) atomicAdd(&cnt[ei[E + e]], 1);
}

// phase A: per-block (1024 elems) local exclusive scan + block sums
__global__ __launch_bounds__(256) void k_scanA(const int* __restrict__ cnt,
                                               int* off, int* psum, int N) {
  __shared__ int sh[256];
  int t = threadIdx.x;
  int base = blockIdx.x * 1024 + t * 4;
  int v[4]; int s = 0;
#pragma unroll
  for (int i = 0; i < 4; i++) {
    int idx = base + i;
    v[i] = (idx < N) ? cnt[idx] : 0;
    s += v[i];
  }
  sh[t] = s;
  __syncthreads();
  for (int d = 1; d < 256; d <<= 1) {
    int x = (t >= d) ? sh[t - d] : 0;
    __syncthreads();
    sh[t] += x;
    __syncthreads();
  }
  int excl = sh[t] - s;
  if (t == 255) psum[blockIdx.x] = sh[255];
  int run = excl;
#pragma unroll
  for (int i = 0; i < 4; i++) {
    int idx = base + i;
    if (idx < N) off[idx] = run;
    run += v[i];
  }
}

// phase B: scan block sums (B <= 256) in a single block
__global__ __launch_bounds__(256) void k_scanB(int* psum, int B) {
  __shared__ int sh[256];
  int t = threadIdx.x;
  int v = (t < B) ? psum[t] : 0;
  sh[t] = v;
  __syncthreads();
  for (int d = 1; d < 256; d <<= 1) {
    int x = (t >= d) ? sh[t - d] : 0;
    __syncthreads();
    sh[t] += x;
    __syncthreads();
  }
  if (t < B) psum[t] = sh[t] - v;  // exclusive
}

// phase C: add block offsets; also init cursor = off and off[N] = E
__global__ __launch_bounds__(256) void k_scanC(int* off, int* cursor,
                                               const int* __restrict__ psum,
                                               int N, int E) {
  int add = psum[blockIdx.x];
  int base = blockIdx.x * 1024 + threadIdx.x * 4;
#pragma unroll
  for (int i = 0; i < 4; i++) {
    int idx = base + i;
    if (idx < N) {
      int v = off[idx] + add;
      off[idx] = v;
      cursor[idx] = v;
    }
  }
  if (blockIdx.x == 0 && threadIdx.x == 0) off[N] = E;
}

// fill: place packed (src | code<<17) per edge into dst-grouped slots
__global__ __launch_bounds__(256) void k_fill(const int* __restrict__ ei,
                                              const int* __restrict__ ea,
                                              int* cursor, int* __restrict__ edat,
                                              int E) {
  int e = blockIdx.x * 256 + threadIdx.x;
  if (e >= E) return;
  int d = ei[E + e];
  int p = atomicAdd(&cursor[d], 1);
  int code = ea[e * 3 + 0] + 6 * ea[e * 3 + 1] + 36 * ea[e * 3 + 2];
  edat[p] = ei[e] | (code << 17);
}

// combined bond-embedding table: tab[a0 + 6*a1 + 36*a2] = e0[a0]+e1[a1]+e2[a2]
__global__ __launch_bounds__(256) void k_bondtab(const float* __restrict__ bond_emb,
                                                 float* __restrict__ tab) {
  int code = blockIdx.x;
  int a0 = code % 6, a1 = (code / 6) % 6, a2 = code / 36;
  int c = threadIdx.x;
  tab[(size_t)code * 256 + c] = bond_emb[(size_t)a0 * 256 + c] +
                                bond_emb[(size_t)(6 + a1) * 256 + c] +
                                bond_emb[(size_t)(12 + a2) * 256 + c];
}

// graph segment boundaries from sorted batch: gstart[g] = lower_bound(batch, g)
__global__ __launch_bounds__(256) void k_gstart(const int* __restrict__ batch,
                                                int* gstart, int N, int G) {
  int g = blockIdx.x * 256 + threadIdx.x;
  if (g > G) return;
  int lo = 0, hi = N;
  while (lo < hi) {
    int mid = (lo + hi) >> 1;
    if (batch[mid] < g) lo = mid + 1; else hi = mid;
  }
  gstart[g] = lo;
}

// ---------------- node encoder (layer 0 h_in) ------------------------------
__global__ __launch_bounds__(256) void k_encode(
    const int* __restrict__ x, const float* __restrict__ atom_emb,
    const float* __restrict__ vn_emb, float* __restrict__ out0, int N)
{
  int t = blockIdx.x * 256 + threadIdx.x;
  int n = t >> 6;
  if (n >= N) return;
  int c = (t & 63) << 2;
  float4 acc = *(const float4*)(vn_emb + c);
#pragma unroll
  for (int f = 0; f < 9; f++) {
    int id = x[n * 9 + f];
    float4 e = *(const float4*)(atom_emb + (size_t)(f * 120 + id) * 256 + c);
    acc.x += e.x; acc.y += e.y; acc.z += e.z; acc.w += e.w;
  }
  *(float4*)(out0 + (size_t)n * 256 + c) = acc;
}

// ---------------- gather: z[d] = (1+eps)*h[d] + sum relu(h[src]+bond[code]) -
__global__ __launch_bounds__(256) void k_gather(
    const float* __restrict__ h, const int* __restrict__ off,
    const int* __restrict__ edat, const float* __restrict__ tab,
    const float* __restrict__ epsPtr, float* __restrict__ z, int N)
{
  int n = (blockIdx.x * 256 + threadIdx.x) >> 6;  // one wave per node
  if (n >= N) return;
  int c = (threadIdx.x & 63) << 2;
  float ep = 1.0f + epsPtr[0];
  float4 hv = *(const float4*)(h + (size_t)n * 256 + c);
  float4 acc;
  acc.x = ep * hv.x; acc.y = ep * hv.y; acc.z = ep * hv.z; acc.w = ep * hv.w;
  int e0 = off[n], e1 = off[n + 1];
  for (int e = e0; e < e1; e++) {
    int sc = edat[e];
    int src = sc & 0x1FFFF;
    int code = ((unsigned)sc) >> 17;
    float4 xs = *(const float4*)(h + (size_t)src * 256 + c);
    float4 b  = *(const float4*)(tab + (size_t)code * 256 + c);
    acc.x += fmaxf(xs.x + b.x, 0.f);
    acc.y += fmaxf(xs.y + b.y, 0.f);
    acc.z += fmaxf(xs.z + b.z, 0.f);
    acc.w += fmaxf(xs.w + b.w, 0.f);
  }
  *(float4*)(z + (size_t)n * 256 + c) = acc;
}

// ---------------- pooled[g] = sum_{n in graph g} h[n]  (sorted batch) ------
__global__ __launch_bounds__(256) void k_pool(const float* __restrict__ h,
                                              const int* __restrict__ gstart,
                                              float* __restrict__ pooled)
{
  int g = blockIdx.x;
  int c = threadIdx.x;
  int n0 = gstart[g], n1 = gstart[g + 1];
  float acc = 0.f;
  for (int n = n0; n < n1; n++) acc += h[(size_t)n * 256 + c];
  pooled[(size_t)g * 256 + c] = acc;
}

// ---------------- h_in for layers 1..4: relu(bn(z)) + vn[batch] ------------
__global__ __launch_bounds__(256) void k_hin(
    const float* __restrict__ z, const float* __restrict__ scale,
    const float* __restrict__ shift, const float* __restrict__ vn,
    const int* __restrict__ batch, float* __restrict__ outp, int N)
{
  int t = blockIdx.x * 256 + threadIdx.x;
  int n = t >> 6;
  if (n >= N) return;
  int c = (t & 63) << 2;
  float4 v  = *(const float4*)(z + (size_t)n * 256 + c);
  float4 sc = *(const float4*)(scale + c);
  float4 sh = *(const float4*)(shift + c);
  float4 h;
  h.x = fmaxf(fmaf(v.x, sc.x, sh.x), 0.f);
  h.y = fmaxf(fmaf(v.y, sc.y, sh.y), 0.f);
  h.z = fmaxf(fmaf(v.z, sc.z, sh.z), 0.f);
  h.w = fmaxf(fmaf(v.w, sc.w, sh.w), 0.f);
  int g = batch[n];
  const float4 vg = *(const float4*)(vn + (size_t)g * 256 + c);
  h.x += vg.x; h.y += vg.y; h.z += vg.z; h.w += vg.w;
  *(float4*)(outp + (size_t)n * 256 + c) = h;
}

// ---------------- final output slot 5: bn(z), no relu ----------------------
__global__ __launch_bounds__(256) void k_out5(
    const float* z, const float* __restrict__ scale,
    const float* __restrict__ shift, float* outp, int N)
{
  int t = blockIdx.x * 256 + threadIdx.x;
  int n = t >> 6;
  if (n >= N) return;
  int c = (t & 63) << 2;
  float4 v  = *(const float4*)(z + (size_t)n * 256 + c);
  float4 sc = *(const float4*)(scale + c);
  float4 sh = *(const float4*)(shift + c);
  float4 h;
  h.x = fmaf(v.x, sc.x, sh.x);
  h.y = fmaf(v.y, sc.y, sh.y);
  h.z = fmaf(v.z, sc.z, sh.z);
  h.w = fmaf(v.w, sc.w, sh.w);
  *(float4*)(outp + (size_t)n * 256 + c) = h;
}

// ---------------- MFMA GEMM: C[M,256] = f(A)[M,256] @ W[256,256] + bias ----
// Wt is bf16, transposed: Wt[n][k]. Block tile 64x256 (full N) so in-place
// C==srcA/srcB is safe (rows read across K-loop before epilogue writes them).
// Also accumulates per-column sum/sumsq of C (post-bias) into stats[512].
#define MODE_BNRELU 1
#define MODE_ADD 2
#define MODE_COPY 3

template <int MODE>
__global__ __launch_bounds__(256, 2) void k_gemm(
    const float* srcA, const float* srcB,
    const float* __restrict__ scale, const float* __restrict__ shift,
    const short* __restrict__ Wt, const float* __restrict__ bias,
    float* C, float* stats, int M)
{
  __shared__ __align__(16) short As[64][72];
  __shared__ __align__(16) short Bs[256][72];
  const int tid = threadIdx.x;
  const int m0 = blockIdx.x * 64;

  float4v acc[4][4];
#pragma unroll
  for (int i = 0; i < 4; i++)
#pragma unroll
    for (int j = 0; j < 4; j++) acc[i][j] = (float4v)0.f;

  const int ar = tid >> 2;           // A-stage row 0..63
  const int ac = (tid & 3) << 4;     // A-stage col chunk (16 floats)
  const int gm = m0 + ar;
  const int lane = tid & 63;
  const int wv = tid >> 6;           // wave 0..3 -> 64-col slice
  const int fr = lane & 15;
  const int kq = (lane >> 4) << 3;   // k offset within 32-wide mfma K

  for (int kt = 0; kt < 4; kt++) {
    const int kb = kt * 64;
    // ---- stage A (compute f32 -> bf16) ----
#pragma unroll
    for (int q = 0; q < 4; q++) {
      int k = kb + ac + q * 4;
      float4 v = make_float4(0.f, 0.f, 0.f, 0.f);
      if (gm < M) {
        if constexpr (MODE == MODE_COPY) {
          v = *(const float4*)(srcA + (size_t)gm * 256 + k);
        } else if constexpr (MODE == MODE_BNRELU) {
          float4 h = *(const float4*)(srcA + (size_t)gm * 256 + k);
          float4 sc = *(const float4*)(scale + k);
          float4 sh = *(const float4*)(shift + k);
          v.x = fmaxf(fmaf(h.x, sc.x, sh.x), 0.f);
          v.y = fmaxf(fmaf(h.y, sc.y, sh.y), 0.f);
          v.z = fmaxf(fmaf(h.z, sc.z, sh.z), 0.f);
          v.w = fmaxf(fmaf(h.w, sc.w, sh.w), 0.f);
        } else {
          float4 h = *(const float4*)(srcA + (size_t)gm * 256 + k);
          float4 g = *(const float4*)(srcB + (size_t)gm * 256 + k);
          v.x = h.x + g.x; v.y = h.y + g.y; v.z = h.z + g.z; v.w = h.w + g.w;
        }
      }
      short4v s;
      s.x = f2bf(v.x); s.y = f2bf(v.y); s.z = f2bf(v.z); s.w = f2bf(v.w);
      *(short4v*)&As[ar][ac + q * 4] = s;
    }
    // ---- stage B (copy bf16 Wt rows) ----
#pragma unroll
    for (int p = 0; p < 8; p++) {
      int n = p * 32 + (tid >> 3);
      int kk8 = (tid & 7) << 3;
      short8 w = *(const short8*)(Wt + (size_t)n * 256 + kb + kk8);
      *(short8*)&Bs[n][kk8] = w;
    }
    __syncthreads();
    // ---- MFMA ----
#pragma unroll
    for (int kk = 0; kk < 2; kk++) {
      short8 a[4], b[4];
#pragma unroll
      for (int mf = 0; mf < 4; mf++)
        a[mf] = *(const short8*)&As[mf * 16 + fr][kk * 32 + kq];
#pragma unroll
      for (int nf = 0; nf < 4; nf++)
        b[nf] = *(const short8*)&Bs[wv * 64 + nf * 16 + fr][kk * 32 + kq];
#pragma unroll
      for (int mf = 0; mf < 4; mf++)
#pragma unroll
        for (int nf = 0; nf < 4; nf++)
          acc[mf][nf] = __builtin_amdgcn_mfma_f32_16x16x32_bf16(
              a[mf], b[nf], acc[mf][nf], 0, 0, 0);
    }
    __syncthreads();
  }

  // ---- epilogue: bias, store, column stats ----
  const int rq = (lane >> 4) << 2;
  float bs[4];
#pragma unroll
  for (int nf = 0; nf < 4; nf++) bs[nf] = bias[wv * 64 + nf * 16 + fr];
  float s1[4] = {0.f, 0.f, 0.f, 0.f}, s2[4] = {0.f, 0.f, 0.f, 0.f};
#pragma unroll
  for (int mf = 0; mf < 4; mf++) {
#pragma unroll
    for (int nf = 0; nf < 4; nf++) {
#pragma unroll
      for (int r = 0; r < 4; r++) {
        int gmm = m0 + mf * 16 + rq + r;
        if (gmm < M) {
          int gn = wv * 64 + nf * 16 + fr;
          float v = acc[mf][nf][r] + bs[nf];
          C[(size_t)gmm * 256 + gn] = v;
          s1[nf] += v;
          s2[nf] += v * v;
        }
      }
    }
  }
#pragma unroll
  for (int nf = 0; nf < 4; nf++) {
    float a = s1[nf];
    a += __shfl_xor(a, 16); a += __shfl_xor(a, 32);
    float b = s2[nf];
    b += __shfl_xor(b, 16); b += __shfl_xor(b, 32);
    if ((lane >> 4) == 0) {
      atomicAdd(&stats[wv * 64 + nf * 16 + lane], a);
      atomicAdd(&stats[256 + wv * 64 + nf * 16 + lane], b);
    }
  }
}

// ---------------------------------------------------------------------------
extern "C" void kernel_launch(void* const* d_in, const int* in_sizes, int n_in,
                              void* d_out, int out_size, void* d_ws, size_t ws_size,
                              hipStream_t stream)
{
  const int*   x        = (const int*)d_in[0];
  const int*   ei       = (const int*)d_in[1];
  const int*   ea       = (const int*)d_in[2];
  const int*   batch    = (const int*)d_in[3];
  const float* atom_emb = (const float*)d_in[4];
  const float* bond_emb = (const float*)d_in[5];
  const float* vn_emb   = (const float*)d_in[6];
  const float* gin_eps  = (const float*)d_in[7];
  const float* cW1      = (const float*)d_in[8];
  const float* cb1      = (const float*)d_in[9];
  const float* cbn_g    = (const float*)d_in[10];
  const float* cbn_b    = (const float*)d_in[11];
  const float* cW2      = (const float*)d_in[12];
  const float* cb2      = (const float*)d_in[13];
  const float* obn_g    = (const float*)d_in[14];
  const float* obn_b    = (const float*)d_in[15];
  const float* vW1      = (const float*)d_in[16];
  const float* vb1      = (const float*)d_in[17];
  const float* vbn1_g   = (const float*)d_in[18];
  const float* vbn1_b   = (const float*)d_in[19];
  const float* vW2      = (const float*)d_in[20];
  const float* vb2      = (const float*)d_in[21];
  const float* vbn2_g   = (const float*)d_in[22];
  const float* vbn2_b   = (const float*)d_in[23];
  (void)n_in; (void)ws_size; (void)out_size;

  const int N = in_sizes[0] / 9;      // 100000
  const int E = in_sizes[1] / 2;      // 300000
  const int G = 4096;

  float* out = (float*)d_out;
  // buf (z1/z2) lives in out slot 5 -- free until the last layer, and the
  // last layer's in-place use is block-row exclusive (full-N GEMM tiling).
  float* buf = out + (size_t)5 * N * 256;

  // workspace layout (~12.9 MB)
  float* pooled = (float*)d_ws;                      // G*256 (also t1, in-place)
  float* statsA = pooled + (size_t)G * 256;          // 4 stages * 512
  float* scaleA = statsA + 2048;                     // 4 stages * (256+256)
  float* vnbuf  = scaleA + 2048;                     // G*256
  float* tab    = vnbuf + (size_t)G * 256;           // 216*256
  short* Wt     = (short*)(tab + 216 * 256);         // 18 * 256*256 bf16
  int*   edat   = (int*)(Wt + 18 * 65536);           // E packed (src | code<<17)
  int*   cnt    = edat + E;                          // N (aliased as cursor)
  int*   off    = cnt + N;                           // N+1
  int*   psum   = off + N + 1;                       // <=128
  int*   gstart = psum + 128;                        // G+1
  int*   cursor = cnt;                               // alias: cnt dead after scanA
  float* t1     = pooled;                            // alias: in-place VN GEMM

  auto sums = [&](int s) { return statsA + s * 512; };
  auto scl  = [&](int s) { return scaleA + s * 512; };
  auto shf  = [&](int s) { return scaleA + s * 512 + 256; };

  dim3 b256(256);
  const int gN = (N * 64 + 255) / 256;      // elementwise grids (4 floats/thread)
  const int gW = (N + 3) / 4;               // one wave per node
  const int gemmN = (N + 63) / 64;
  const int gemmG = G / 64;
  const int nb1024 = (N + 1023) / 1024;     // scan blocks (98 <= 256)
  const float invN = 1.0f / (float)N, invG = 1.0f / (float)G;

  // one-time prep
  k_transpose_weights<<<dim3(64, 18), b256, 0, stream>>>(cW1, cW2, vW1, vW2, Wt);
  k_vninit<<<G, b256, 0, stream>>>(vnbuf, vn_emb);
  k_bondtab<<<216, b256, 0, stream>>>(bond_emb, tab);
  k_gstart<<<(G + 1 + 255) / 256, b256, 0, stream>>>(batch, gstart, N, G);
  // CSR by dst
  hipMemsetAsync(cnt, 0, (size_t)N * 4, stream);
  k_count<<<(E + 255) / 256, b256, 0, stream>>>(ei, cnt, E);
  k_scanA<<<nb1024, b256, 0, stream>>>(cnt, off, psum, N);
  k_scanB<<<1, b256, 0, stream>>>(psum, nb1024);
  k_scanC<<<nb1024, b256, 0, stream>>>(off, cursor, psum, N, E);
  k_fill<<<(E + 255) / 256, b256, 0, stream>>>(ei, ea, cursor, edat, E);
  // layer-0 h_in
  k_encode<<<gN, b256, 0, stream>>>(x, atom_emb, vn_emb, out, N);

  for (int l = 0; l < 5; l++) {
    const float* hin = out + (size_t)l * N * 256;
    hipMemsetAsync(statsA, 0, 2048 * 4, stream);
    // z0 = (1+eps)*hin + sum_{e: dst=n} relu(hin[src]+bond)   (atomic-free)
    k_gather<<<gW, b256, 0, stream>>>(hin, off, edat, tab, gin_eps + l, buf, N);
    // z1 = z0 @ W1 + b1   (in place: C aliases srcA rows, block-row exclusive)
    k_gemm<MODE_COPY><<<gemmN, b256, 0, stream>>>(
        buf, nullptr, nullptr, nullptr,
        Wt + (size_t)l * 65536, cb1 + l * 256, buf, sums(0), N);
    k_finalize<<<1, b256, 0, stream>>>(sums(0), cbn_g + l * 256, cbn_b + l * 256,
                                       scl(0), shf(0), invN);
    // z2 = relu(bn(z1)) @ W2 + b2          (in place)
    k_gemm<MODE_BNRELU><<<gemmN, b256, 0, stream>>>(
        buf, nullptr, scl(0), shf(0),
        Wt + (size_t)(5 + l) * 65536, cb2 + l * 256, buf, sums(1), N);
    k_finalize<<<1, b256, 0, stream>>>(sums(1), obn_g + l * 256, obn_b + l * 256,
                                       scl(1), shf(1), invN);
    if (l < 4) {
      // pooled = segment_sum(h_in, batch)  (sorted batch, atomic-free)
      k_pool<<<G, b256, 0, stream>>>(hin, gstart, pooled);
      // virtual-node MLP (t1 aliases pooled; in-place row-exclusive GEMM)
      k_gemm<MODE_ADD><<<gemmG, b256, 0, stream>>>(
          pooled, vnbuf, nullptr, nullptr,
          Wt + (size_t)(10 + l) * 65536, vb1 + l * 256, t1, sums(2), G);
      k_finalize<<<1, b256, 0, stream>>>(sums(2), vbn1_g + l * 256, vbn1_b + l * 256,
                                         scl(2), shf(2), invG);
      k_gemm<MODE_BNRELU><<<gemmG, b256, 0, stream>>>(
          t1, nullptr, scl(2), shf(2),
          Wt + (size_t)(14 + l) * 65536, vb2 + l * 256, vnbuf, sums(3), G);
      k_finalize<<<1, b256, 0, stream>>>(sums(3), vbn2_g + l * 256, vbn2_b + l * 256,
                                         scl(3), shf(3), invG);
      k_vnapply<<<G, b256, 0, stream>>>(vnbuf, scl(3), shf(3));
      // h_in(l+1) = relu(bn(z2)) + vn[batch]
      k_hin<<<gN, b256, 0, stream>>>(buf, scl(1), shf(1), vnbuf, batch,
                                     out + (size_t)(l + 1) * N * 256, N);
    } else {
      // out[5] = bn(z2), no relu (in place over buf)
      k_out5<<<gN, b256, 0, stream>>>(buf, scl(1), shf(1),
                                      out + (size_t)5 * N * 256, N);
    }
  }
}